// Round 4
// baseline (1298.009 us; speedup 1.0000x reference)
//
#include <hip/hip_runtime.h>
#include <hip/hip_bf16.h>
#include <math.h>

#define Bb 16
#define DIN 16
#define LL 4096
#define HH 256
#define NN2 32
#define NLAY 4
#define HN (HH*NN2)
#define CH2 64
#define NC2 (LL/CH2)   // 64 chunks
#define BN 32          // mm l-tile

typedef __attribute__((ext_vector_type(8))) short short8;
typedef __attribute__((ext_vector_type(4))) short short4v;
typedef __attribute__((ext_vector_type(4))) float f32x4;
typedef __attribute__((ext_vector_type(2))) float f32x2;
typedef unsigned short u16;

__device__ inline f32x2 pkfma(f32x2 a, f32x2 b, f32x2 c) {
  return __builtin_elementwise_fma(a, b, c);
}
__device__ inline u16 f2bf(float f) {
  unsigned int x = __float_as_uint(f);
  unsigned int r = x + 0x7FFFu + ((x >> 16) & 1u);   // RNE
  return (u16)(r >> 16);
}
__device__ inline float bf2f(u16 u) {
  return __uint_as_float(((unsigned int)u) << 16);
}

// ---------------- encoder ----------------
__global__ __launch_bounds__(256) void enc_kernel(const float* __restrict__ x,
    const float* __restrict__ ew, const float* __restrict__ eb,
    float* __restrict__ hbuf) {
  int blk = blockIdx.x;
  int tile = blk & 15;
  int h = (blk >> 4) & (HH - 1);
  int b = blk >> 12;
  int l = tile * 256 + threadIdx.x;
  const float* xb = x + (size_t)b * DIN * LL + l;
  float acc = eb[h];
  #pragma unroll
  for (int i = 0; i < DIN; ++i)
    acc = fmaf(xb[(size_t)i * LL], ew[i * HH + h], acc);
  hbuf[((size_t)(b * HH + h)) * LL + l] = acc;
}

// ---------------- per-layer SSM coefficients ----------------
__global__ __launch_bounds__(256) void coef_kernel(
    const float* __restrict__ log_dt, const float* __restrict__ Are,
    const float* __restrict__ Aim, const float* __restrict__ Cre,
    const float* __restrict__ Cim, float* __restrict__ coef) {
  int idx = blockIdx.x * 256 + threadIdx.x;
  if (idx >= HN) return;
  int h = idx >> 5;
  float dt = expf(log_dt[h]);
  float ar = -expf(Are[idx]);
  float ai = Aim[idx];
  float dre = ar * dt, dim = ai * dt;
  float er = expf(dre);
  float wr = er * cosf(dim);
  float wi = er * sinf(dim);
  float nr = wr - 1.f, ni = wi;
  float inv = 1.f / (ar * ar + ai * ai);
  float qr = (nr * ar + ni * ai) * inv;
  float qi = (ni * ar - nr * ai) * inv;
  float crv = Cre[idx], civ = Cim[idx];
  coef[idx]          = wr;
  coef[HN + idx]     = wi;
  coef[2 * HN + idx] = 2.f * (crv * qr - civ * qi);
  coef[3 * HN + idx] = 2.f * (crv * qi + civ * qr);
}

// ---------------- W pack: hi/lo bf16 planes, transposed Wp[d][h] ----------------
__global__ __launch_bounds__(256) void wpack_kernel(const float* __restrict__ W,
                                                    u16* __restrict__ Wh,
                                                    u16* __restrict__ Wl) {
  int idx = blockIdx.x * 256 + threadIdx.x;  // idx = d*256 + h
  int d = idx >> 8, h = idx & 255;
  float w = W[h * HH + d];
  u16 hi = f2bf(w);
  u16 lo = f2bf(w - bf2f(hi));
  Wh[idx] = hi;
  Wl[idx] = lo;
}

// ---------------- fused SSM: packed-f32 recurrence + skip + gelu -> hi/lo bf16 planes ----------------
__global__ __launch_bounds__(512, 8) void s4_kernel(
    const float* __restrict__ zg, const float* __restrict__ coef,
    const float* __restrict__ Dvec, u16* __restrict__ ghi,
    u16* __restrict__ glo) {
  __shared__ float z_lds[LL + 4 * NC2];   // index l -> l + 4*(l>>6), chunk stride 68
  __shared__ float st[NC2 * 66];
  int bh = blockIdx.x;
  int h = bh & (HH - 1);
  int t = threadIdx.x;
  const float* zrow = zg + (size_t)bh * LL;
  #pragma unroll
  for (int p = 0; p < 2; ++p) {
    int i4 = p * 512 + t;
    float4 v = ((const float4*)zrow)[i4];
    int l = i4 * 4;
    int base = l + ((l >> 6) << 2);
    *(float4*)&z_lds[base] = v;
  }
  float Dh = Dvec[h];
  int c = t >> 3;
  int sub = t & 7;
  // packed coefficients: pair p holds states k=2p, 2p+1 (n = sub*4 + k)
  f32x2 wrp[2], wip[2], nwip[2], crp[2], ncip[2];
  const float* cf = coef + h * NN2;
  #pragma unroll
  for (int p = 0; p < 2; ++p) {
    int n0 = sub * 4 + 2 * p;
    wrp[p]  = (f32x2){cf[n0],          cf[n0 + 1]};
    wip[p]  = (f32x2){cf[HN + n0],     cf[HN + n0 + 1]};
    crp[p]  = (f32x2){cf[2 * HN + n0], cf[2 * HN + n0 + 1]};
    ncip[p] = (f32x2){-cf[3 * HN + n0], -cf[3 * HN + n0 + 1]};
    nwip[p] = -wip[p];
  }
  // w^2 for 2-step phase-1
  f32x2 w2r[2], w2i[2], nw2i[2];
  #pragma unroll
  for (int p = 0; p < 2; ++p) {
    w2r[p] = pkfma(wrp[p], wrp[p], -(wip[p] * wip[p]));
    w2i[p] = 2.f * (wrp[p] * wip[p]);
    nw2i[p] = -w2i[p];
  }
  __syncthreads();
  int zb = c * 68;
  int sb = c * 66 + sub * 8;
  // phase 1: chunk-local recurrence, 2 steps fused via w^2
  f32x2 srp[2] = {(f32x2){0.f, 0.f}, (f32x2){0.f, 0.f}};
  f32x2 sip[2] = {(f32x2){0.f, 0.f}, (f32x2){0.f, 0.f}};
  #pragma unroll 4
  for (int j4 = 0; j4 < 16; ++j4) {
    float4 z4 = *(const float4*)&z_lds[zb + 4 * j4];
    {
      f32x2 z1v = (f32x2){z4.x, z4.x};
      f32x2 z2v = (f32x2){z4.y, z4.y};
      #pragma unroll
      for (int p = 0; p < 2; ++p) {
        f32x2 zcr = pkfma(z1v, wrp[p], z2v);
        f32x2 zci = z1v * wip[p];
        f32x2 nr = pkfma(w2r[p], srp[p], pkfma(nw2i[p], sip[p], zcr));
        f32x2 ni = pkfma(w2i[p], srp[p], pkfma(w2r[p], sip[p], zci));
        srp[p] = nr; sip[p] = ni;
      }
    }
    {
      f32x2 z1v = (f32x2){z4.z, z4.z};
      f32x2 z2v = (f32x2){z4.w, z4.w};
      #pragma unroll
      for (int p = 0; p < 2; ++p) {
        f32x2 zcr = pkfma(z1v, wrp[p], z2v);
        f32x2 zci = z1v * wip[p];
        f32x2 nr = pkfma(w2r[p], srp[p], pkfma(nw2i[p], sip[p], zcr));
        f32x2 ni = pkfma(w2i[p], srp[p], pkfma(w2r[p], sip[p], zci));
        srp[p] = nr; sip[p] = ni;
      }
    }
  }
  st[sb + 0] = srp[0].x; st[sb + 1] = sip[0].x;
  st[sb + 2] = srp[0].y; st[sb + 3] = sip[0].y;
  st[sb + 4] = srp[1].x; st[sb + 5] = sip[1].x;
  st[sb + 6] = srp[1].y; st[sb + 7] = sip[1].y;
  // M = w^CH2 (6 squarings), scalar (one-time)
  float prS[4], piS[4], xrS[4], xiS[4];
  #pragma unroll
  for (int k = 0; k < 4; ++k) {
    prS[k] = wrp[k >> 1][k & 1];
    piS[k] = wip[k >> 1][k & 1];
    xrS[k] = (k & 1) ? srp[k >> 1].y : srp[k >> 1].x;
    xiS[k] = (k & 1) ? sip[k >> 1].y : sip[k >> 1].x;
  }
  #pragma unroll
  for (int q = 0; q < 6; ++q) {
    #pragma unroll
    for (int k = 0; k < 4; ++k) {
      float t0 = prS[k] * prS[k] - piS[k] * piS[k];
      piS[k] = 2.f * prS[k] * piS[k];
      prS[k] = t0;
    }
  }
  __syncthreads();
  // Kogge-Stone inclusive scan over chunks
  for (int d = 1; d < NC2; d <<= 1) {
    float qr[4], qi[4];
    if (c >= d) {
      int nb = (c - d) * 66 + sub * 8;
      #pragma unroll
      for (int k = 0; k < 4; ++k) {
        qr[k] = st[nb + 2 * k];
        qi[k] = st[nb + 2 * k + 1];
      }
    }
    __syncthreads();
    if (c >= d) {
      #pragma unroll
      for (int k = 0; k < 4; ++k) {
        xrS[k] = fmaf(prS[k], qr[k], fmaf(-piS[k], qi[k], xrS[k]));
        xiS[k] = fmaf(prS[k], qi[k], fmaf(piS[k], qr[k], xiS[k]));
      }
    }
    #pragma unroll
    for (int k = 0; k < 4; ++k) {
      float t0 = prS[k] * prS[k] - piS[k] * piS[k];
      piS[k] = 2.f * prS[k] * piS[k];
      prS[k] = t0;
    }
    #pragma unroll
    for (int k = 0; k < 4; ++k) {
      st[sb + 2 * k] = xrS[k];
      st[sb + 2 * k + 1] = xiS[k];
    }
    __syncthreads();
  }
  // init state for this chunk = inclusive prefix of chunk c-1
  if (c == 0) {
    srp[0] = (f32x2){0.f, 0.f}; srp[1] = (f32x2){0.f, 0.f};
    sip[0] = (f32x2){0.f, 0.f}; sip[1] = (f32x2){0.f, 0.f};
  } else {
    int nb = (c - 1) * 66 + sub * 8;
    #pragma unroll
    for (int p = 0; p < 2; ++p) {
      srp[p] = (f32x2){st[nb + 4 * p], st[nb + 4 * p + 2]};
      sip[p] = (f32x2){st[nb + 4 * p + 1], st[nb + 4 * p + 3]};
    }
  }
  // phase 3: recurrence with correct init + output; write v = z*D + y in place
  #pragma unroll 2
  for (int j4 = 0; j4 < 16; ++j4) {
    float4 z4 = *(const float4*)&z_lds[zb + 4 * j4];
    #pragma unroll
    for (int jj = 0; jj < 4; ++jj) {
      float zv = (jj == 0) ? z4.x : (jj == 1) ? z4.y : (jj == 2) ? z4.z : z4.w;
      f32x2 zv2 = (f32x2){zv, zv};
      f32x2 yp = (f32x2){0.f, 0.f};
      #pragma unroll
      for (int p = 0; p < 2; ++p) {
        f32x2 nr = pkfma(wrp[p], srp[p], pkfma(nwip[p], sip[p], zv2));
        f32x2 ni = pkfma(wip[p], srp[p], wrp[p] * sip[p]);
        srp[p] = nr; sip[p] = ni;
        yp = pkfma(crp[p], nr, pkfma(ncip[p], ni, yp));
      }
      float y = yp.x + yp.y;
      y += __shfl_xor(y, 1);
      y += __shfl_xor(y, 2);
      y += __shfl_xor(y, 4);
      if (sub == 0) z_lds[zb + 4 * j4 + jj] = fmaf(zv, Dh, y);
    }
  }
  __syncthreads();
  // epilogue: gelu (sigmoid form) -> split bf16 planes, ushort2 stores
  u16* ghrow = ghi + (size_t)bh * LL;
  u16* glrow = glo + (size_t)bh * LL;
  #pragma unroll
  for (int p = 0; p < 4; ++p) {
    int l = p * 1024 + 2 * t;
    f32x2 v2 = *(const f32x2*)&z_lds[l + ((l >> 6) << 2)];
    float va = v2.x, vb = v2.y;
    float ua = 1.5957691216057308f * fmaf(0.044715f * va, va * va, va);
    float ub = 1.5957691216057308f * fmaf(0.044715f * vb, vb * vb, vb);
    va = va / (1.f + __expf(-ua));
    vb = vb / (1.f + __expf(-ub));
    u16 ha = f2bf(va), hb = f2bf(vb);
    u16 la = f2bf(va - bf2f(ha)), lb2 = f2bf(vb - bf2f(hb));
    ushort2 hv; hv.x = ha; hv.y = hb;
    ushort2 lv; lv.x = la; lv.y = lb2;
    *(ushort2*)&ghrow[l] = hv;
    *(ushort2*)&glrow[l] = lv;
  }
}

// ---------------- MFMA matmul + bias + residual + LayerNorm (split bf16 planes) ----------------
__global__ __launch_bounds__(256, 4) void mm_mfma_ln_kernel(
    const u16* __restrict__ ghi, const u16* __restrict__ glo,
    float* __restrict__ h_buf, const u16* __restrict__ Wh,
    const u16* __restrict__ Wl, const float* __restrict__ bo,
    const float* __restrict__ lw, const float* __restrict__ lb) {
  __shared__ u16 gt_hi[BN * HH];   // [l][h] swizzled on 4-ushort granules
  __shared__ u16 gt_lo[BN * HH];
  __shared__ float red_s[4][BN];
  __shared__ float red_q[4][BN];
  int blk = blockIdx.x;
  int b = blk >> 7;
  int l0 = (blk & 127) * BN;
  int t = threadIdx.x;
  const u16* gh = ghi + (size_t)b * HH * LL + l0;
  const u16* gl = glo + (size_t)b * HH * LL + l0;
  #pragma unroll
  for (int p = 0; p < 4; ++p) {
    int hh = p * 64 + (t >> 2);
    int lq = (t & 3) * 8;
    uint4 vh = *(const uint4*)(gh + (size_t)hh * LL + lq);
    uint4 vl = *(const uint4*)(gl + (size_t)hh * LL + lq);
    unsigned int wh[4] = {vh.x, vh.y, vh.z, vh.w};
    unsigned int wl[4] = {vl.x, vl.y, vl.z, vl.w};
    #pragma unroll
    for (int j = 0; j < 8; ++j) {
      int l = lq + j;
      int xm = (l & 7) ^ ((l >> 3) & 3);
      int g4 = (hh >> 2) ^ xm;
      int idx = l * HH + g4 * 4 + (hh & 3);
      unsigned int word = (j & 1) ? (wh[j >> 1] >> 16) : (wh[j >> 1] & 0xFFFFu);
      gt_hi[idx] = (u16)word;
      word = (j & 1) ? (wl[j >> 1] >> 16) : (wl[j >> 1] & 0xFFFFu);
      gt_lo[idx] = (u16)word;
    }
  }
  __syncthreads();
  int wv = t >> 6, lane = t & 63;
  int row16 = lane & 15, kgrp = lane >> 4;
  f32x4 acc[4][2];
  #pragma unroll
  for (int di = 0; di < 4; ++di)
    #pragma unroll
    for (int li = 0; li < 2; ++li)
      acc[di][li] = (f32x4){0.f, 0.f, 0.f, 0.f};
  const u16* whB = Wh + (size_t)(wv * 64) * HH;
  const u16* wlB = Wl + (size_t)(wv * 64) * HH;
  #pragma unroll 2
  for (int ks = 0; ks < 8; ++ks) {
    int h0 = ks * 32;
    short8 Bhi[2], Blo[2];
    #pragma unroll
    for (int li = 0; li < 2; ++li) {
      int l = li * 16 + row16;
      int xm = (l & 7) ^ ((l >> 3) & 3);
      int g4a = ((h0 >> 2) + kgrp) ^ xm;
      int g4b = ((h0 >> 2) + kgrp + 4) ^ xm;
      short4v h0v = *(const short4v*)&gt_hi[l * HH + g4a * 4];
      short4v h1v = *(const short4v*)&gt_hi[l * HH + g4b * 4];
      short4v l0v = *(const short4v*)&gt_lo[l * HH + g4a * 4];
      short4v l1v = *(const short4v*)&gt_lo[l * HH + g4b * 4];
      Bhi[li] = __builtin_shufflevector(h0v, h1v, 0, 1, 2, 3, 4, 5, 6, 7);
      Blo[li] = __builtin_shufflevector(l0v, l1v, 0, 1, 2, 3, 4, 5, 6, 7);
    }
    #pragma unroll
    for (int di = 0; di < 4; ++di) {
      int d = di * 16 + row16;
      const u16* pAh = whB + (size_t)d * HH + h0 + kgrp * 4;
      const u16* pAl = wlB + (size_t)d * HH + h0 + kgrp * 4;
      short4v a0 = *(const short4v*)pAh;
      short4v a1 = *(const short4v*)(pAh + 16);
      short4v b0 = *(const short4v*)pAl;
      short4v b1 = *(const short4v*)(pAl + 16);
      short8 Ahi = __builtin_shufflevector(a0, a1, 0, 1, 2, 3, 4, 5, 6, 7);
      short8 Alo = __builtin_shufflevector(b0, b1, 0, 1, 2, 3, 4, 5, 6, 7);
      #pragma unroll
      for (int li = 0; li < 2; ++li) {
        acc[di][li] = __builtin_amdgcn_mfma_f32_16x16x32_bf16(Ahi, Bhi[li], acc[di][li], 0, 0, 0);
        acc[di][li] = __builtin_amdgcn_mfma_f32_16x16x32_bf16(Ahi, Blo[li], acc[di][li], 0, 0, 0);
        acc[di][li] = __builtin_amdgcn_mfma_f32_16x16x32_bf16(Alo, Bhi[li], acc[di][li], 0, 0, 0);
      }
    }
  }
  // bias + residual
  const float* hb = h_buf + (size_t)b * HH * LL + l0;
  #pragma unroll
  for (int di = 0; di < 4; ++di) {
    #pragma unroll
    for (int r = 0; r < 4; ++r) {
      int d = wv * 64 + di * 16 + kgrp * 4 + r;
      float bov = bo[d];
      #pragma unroll
      for (int li = 0; li < 2; ++li) {
        int l = li * 16 + row16;
        acc[di][li][r] += bov + hb[(size_t)d * LL + l];
      }
    }
  }
  // LN stats
  #pragma unroll
  for (int li = 0; li < 2; ++li) {
    float s = 0.f, q = 0.f;
    #pragma unroll
    for (int di = 0; di < 4; ++di)
      #pragma unroll
      for (int r = 0; r < 4; ++r) {
        float v = acc[di][li][r];
        s += v;
        q = fmaf(v, v, q);
      }
    s += __shfl_xor(s, 16); s += __shfl_xor(s, 32);
    q += __shfl_xor(q, 16); q += __shfl_xor(q, 32);
    if (lane < 16) {
      red_s[wv][li * 16 + lane] = s;
      red_q[wv][li * 16 + lane] = q;
    }
  }
  __syncthreads();
  float mu[2], rstd[2];
  #pragma unroll
  for (int li = 0; li < 2; ++li) {
    int cl = li * 16 + row16;
    float s = red_s[0][cl] + red_s[1][cl] + red_s[2][cl] + red_s[3][cl];
    float q = red_q[0][cl] + red_q[1][cl] + red_q[2][cl] + red_q[3][cl];
    float m = s * (1.f / 256.f);
    float var = q * (1.f / 256.f) - m * m;
    mu[li] = m;
    rstd[li] = rsqrtf(var + 1e-5f);
  }
  float* hw = h_buf + (size_t)b * HH * LL + l0;
  #pragma unroll
  for (int di = 0; di < 4; ++di) {
    #pragma unroll
    for (int r = 0; r < 4; ++r) {
      int d = wv * 64 + di * 16 + kgrp * 4 + r;
      float lwv = lw[d], lbv = lb[d];
      #pragma unroll
      for (int li = 0; li < 2; ++li) {
        int l = li * 16 + row16;
        hw[(size_t)d * LL + l] = (acc[di][li][r] - mu[li]) * rstd[li] * lwv + lbv;
      }
    }
  }
}

// ---------------- decoder ----------------
__global__ __launch_bounds__(256) void dec_kernel(
    const float* __restrict__ hbuf, const float* __restrict__ dw,
    const float* __restrict__ db, float* __restrict__ outp) {
  __shared__ float dwl[HH * DIN];
  int blk = blockIdx.x;
  int b = blk >> 4;
  int l0 = (blk & 15) * 256;
  int t = threadIdx.x;
  #pragma unroll
  for (int p = 0; p < 16; ++p) dwl[p * 256 + t] = dw[p * 256 + t];
  __syncthreads();
  float acc[DIN];
  #pragma unroll
  for (int d = 0; d < DIN; ++d) acc[d] = db[d];
  const float* hb = hbuf + (size_t)b * HH * LL + l0;
  for (int hh = 0; hh < HH; ++hh) {
    float v = hb[(size_t)hh * LL + t];
    #pragma unroll
    for (int d = 0; d < DIN; ++d)
      acc[d] = fmaf(v, dwl[hh * DIN + d], acc[d]);
  }
  float* ob = outp + (size_t)b * DIN * LL + l0;
  #pragma unroll
  for (int d = 0; d < DIN; ++d) ob[(size_t)d * LL + t] = acc[d];
}

extern "C" void kernel_launch(void* const* d_in, const int* in_sizes, int n_in,
                              void* d_out, int out_size, void* d_ws, size_t ws_size,
                              hipStream_t stream) {
  const float* x      = (const float*)d_in[0];
  const float* enc_w  = (const float*)d_in[1];
  const float* enc_b  = (const float*)d_in[2];
  const float* log_dt = (const float*)d_in[3];
  const float* A_re   = (const float*)d_in[4];
  const float* A_im   = (const float*)d_in[5];
  const float* C_re   = (const float*)d_in[6];
  const float* C_im   = (const float*)d_in[7];
  const float* Dv     = (const float*)d_in[8];
  const float* W_out  = (const float*)d_in[9];
  const float* b_out  = (const float*)d_in[10];
  const float* ln_w   = (const float*)d_in[11];
  const float* ln_b   = (const float*)d_in[12];
  const float* dec_w  = (const float*)d_in[13];
  const float* dec_b  = (const float*)d_in[14];
  float* out = (float*)d_out;

  float* h_buf = (float*)d_ws;
  u16* g_hi = (u16*)(h_buf + (size_t)Bb * HH * LL);
  u16* g_lo = g_hi + (size_t)Bb * HH * LL;
  float* coef = (float*)(g_lo + (size_t)Bb * HH * LL);
  u16* Wh = (u16*)(coef + 4 * HN);
  u16* Wl = Wh + HH * HH;

  enc_kernel<<<Bb * HH * (LL / 256), 256, 0, stream>>>(x, enc_w, enc_b, h_buf);
  for (int i = 0; i < NLAY; ++i) {
    coef_kernel<<<HN / 256, 256, 0, stream>>>(log_dt + i * HH, A_re + i * HN,
                                              A_im + i * HN, C_re + i * HN,
                                              C_im + i * HN, coef);
    wpack_kernel<<<HH * HH / 256, 256, 0, stream>>>(W_out + (size_t)i * HH * HH, Wh, Wl);
    s4_kernel<<<Bb * HH, 512, 0, stream>>>(h_buf, coef, Dv + i * HH, g_hi, g_lo);
    mm_mfma_ln_kernel<<<Bb * (LL / BN), 256, 0, stream>>>(
        g_hi, g_lo, h_buf, Wh, Wl, b_out + i * HH, ln_w + i * HH, ln_b + i * HH);
  }
  dec_kernel<<<Bb * (LL / 256), 256, 0, stream>>>(h_buf, dec_w, dec_b, out);
}

// Round 5
// 857.147 us; speedup vs baseline: 1.5143x; 1.5143x over previous
//
#include <hip/hip_runtime.h>
#include <hip/hip_bf16.h>
#include <math.h>

#define Bb 16
#define DIN 16
#define LL 4096
#define HH 256
#define NN2 32
#define NLAY 4
#define HN (HH*NN2)
#define BN 32          // mm l-tile

typedef __attribute__((ext_vector_type(8))) short short8;
typedef __attribute__((ext_vector_type(4))) short short4v;
typedef __attribute__((ext_vector_type(4))) float f32x4;
typedef unsigned short u16;

__device__ inline u16 f2bf(float f) {
  unsigned int x = __float_as_uint(f);
  unsigned int r = x + 0x7FFFu + ((x >> 16) & 1u);   // RNE
  return (u16)(r >> 16);
}
__device__ inline float bf2f(u16 u) {
  return __uint_as_float(((unsigned int)u) << 16);
}
__device__ inline unsigned int packsplit(float v) {
  u16 hi = f2bf(v);
  u16 lo = f2bf(v - bf2f(hi));
  return (((unsigned int)hi) << 16) | lo;
}
// fragment loader: 4 u16 at p, 4 u16 at p+16 (k and k+16 halves)
__device__ inline short8 ld8(const u16* p) {
  short4v a = *(const short4v*)p;
  short4v b = *(const short4v*)(p + 16);
  return __builtin_shufflevector(a, b, 0, 1, 2, 3, 4, 5, 6, 7);
}

// ---------------- encoder ----------------
__global__ __launch_bounds__(256) void enc_kernel(const float* __restrict__ x,
    const float* __restrict__ ew, const float* __restrict__ eb,
    float* __restrict__ hbuf) {
  int blk = blockIdx.x;
  int tile = blk & 15;
  int h = (blk >> 4) & (HH - 1);
  int b = blk >> 12;
  int l = tile * 256 + threadIdx.x;
  const float* xb = x + (size_t)b * DIN * LL + l;
  float acc = eb[h];
  #pragma unroll
  for (int i = 0; i < DIN; ++i)
    acc = fmaf(xb[(size_t)i * LL], ew[i * HH + h], acc);
  hbuf[((size_t)(b * HH + h)) * LL + l] = acc;
}

// ---------------- per-layer SSM coefficients ----------------
// coef: [0,HN) w_re | [HN) w_im | [2HN) 2Cc_re | [3HN) 2Cc_im | [4HN) w64_re | [5HN) w64_im
__global__ __launch_bounds__(256) void coef_kernel(
    const float* __restrict__ log_dt, const float* __restrict__ Are,
    const float* __restrict__ Aim, const float* __restrict__ Cre,
    const float* __restrict__ Cim, float* __restrict__ coef) {
  int idx = blockIdx.x * 256 + threadIdx.x;
  if (idx >= HN) return;
  int h = idx >> 5;
  float dt = expf(log_dt[h]);
  float ar = -expf(Are[idx]);
  float ai = Aim[idx];
  float dre = ar * dt, dim = ai * dt;
  float er = expf(dre);
  float wr = er * cosf(dim);
  float wi = er * sinf(dim);
  float nr = wr - 1.f, ni = wi;
  float inv = 1.f / (ar * ar + ai * ai);
  float qr = (nr * ar + ni * ai) * inv;
  float qi = (ni * ar - nr * ai) * inv;
  float crv = Cre[idx], civ = Cim[idx];
  coef[idx]          = wr;
  coef[HN + idx]     = wi;
  coef[2 * HN + idx] = 2.f * (crv * qr - civ * qi);
  coef[3 * HN + idx] = 2.f * (crv * qi + civ * qr);
  float pr = wr, pi = wi;
  #pragma unroll
  for (int q = 0; q < 6; ++q) {
    float t0 = pr * pr - pi * pi;
    pi = 2.f * pr * pi;
    pr = t0;
  }
  coef[4 * HN + idx] = pr;
  coef[5 * HN + idx] = pi;
}

// ---------------- per-layer basis: T (Toeplitz), M (state map), E (correction) ----------------
// One block per h. T[j][i]=K[j-i] (j>=i); M[2n][i]=Re(w^(63-i)), M[2n+1][i]=Im;
// E[j][2n]=Re(C w^(j+1)), E[j][2n+1]=-Im(C w^(j+1)). All hi/lo bf16 planes [h][64][64].
__global__ __launch_bounds__(256) void basis_kernel(
    const float* __restrict__ coef,
    u16* __restrict__ Th, u16* __restrict__ Tl,
    u16* __restrict__ Mh, u16* __restrict__ Ml,
    u16* __restrict__ Eh, u16* __restrict__ El) {
  __shared__ float K_l[64];
  int h = blockIdx.x;
  int t = threadIdx.x;
  if (t < 32) {
    int n = t;
    float wr = coef[h * 32 + n], wi = coef[HN + h * 32 + n];
    float cr = coef[2 * HN + h * 32 + n], ci = coef[3 * HN + h * 32 + n];
    float vr = 1.f, vi = 0.f;
    for (int m = 0; m <= 64; ++m) {
      float e = cr * vr - ci * vi;
      float f = -(cr * vi + ci * vr);
      float s = e;
      s += __shfl_xor(s, 1); s += __shfl_xor(s, 2); s += __shfl_xor(s, 4);
      s += __shfl_xor(s, 8); s += __shfl_xor(s, 16);
      if (m <= 63) {
        if (n == 0) K_l[m] = s;
        int i = 63 - m;
        size_t mb = ((size_t)h * 64 + 2 * n) * 64 + i;
        u16 hr = f2bf(vr);
        Mh[mb] = hr; Ml[mb] = f2bf(vr - bf2f(hr));
        u16 hi2 = f2bf(vi);
        Mh[mb + 64] = hi2; Ml[mb + 64] = f2bf(vi - bf2f(hi2));
      }
      if (m >= 1) {
        size_t ebase = ((size_t)h * 64 + (m - 1)) * 64 + 2 * n;
        u16 he = f2bf(e);
        Eh[ebase] = he; El[ebase] = f2bf(e - bf2f(he));
        u16 hf = f2bf(f);
        Eh[ebase + 1] = hf; El[ebase + 1] = f2bf(f - bf2f(hf));
      }
      float nvr = vr * wr - vi * wi;
      float nvi = vr * wi + vi * wr;
      vr = nvr; vi = nvi;
    }
  }
  __syncthreads();
  #pragma unroll
  for (int p = 0; p < 16; ++p) {
    int id = p * 256 + t;
    int j = id >> 6, i = id & 63;
    float kv = (j >= i) ? K_l[j - i] : 0.f;
    u16 hi = f2bf(kv);
    size_t tb = ((size_t)h * 64 + j) * 64 + i;
    Th[tb] = hi; Tl[tb] = f2bf(kv - bf2f(hi));
  }
}

// ---------------- W pack: Wp[d*256+h] = split(W[h][d]) (round-3 proven) ----------------
__global__ __launch_bounds__(256) void wpack_kernel(const float* __restrict__ W,
                                                    unsigned int* __restrict__ Wp) {
  int idx = blockIdx.x * 256 + threadIdx.x;
  int d = idx >> 8, h = idx & 255;
  Wp[idx] = packsplit(W[h * HH + d]);
}

// ---------------- MFMA SSM: S_end=M@Z, scan, Y=T@Z+E@S_init, skip+gelu -> packed g ----------------
// One block per (b,h): 256 threads = 4 waves; waves own 16-row bands of all 64x64 matmuls.
__global__ __launch_bounds__(256, 3) void s4_mfma_kernel(
    const float* __restrict__ zg, const float* __restrict__ coef,
    const float* __restrict__ Dvec,
    const u16* __restrict__ Th, const u16* __restrict__ Tl,
    const u16* __restrict__ Mh, const u16* __restrict__ Ml,
    const u16* __restrict__ Eh, const u16* __restrict__ El,
    unsigned int* __restrict__ gout) {
  __shared__ u16 zh[64 * 68], zl[64 * 68];   // z planes, [chunk][i] pad 68
  __shared__ u16 sh[64 * 68], sl[64 * 68];   // S_init planes, [chunk][dim]
  __shared__ float st[64 * 68];              // scan buffer; reused as u32 pack-out
  int bh = blockIdx.x, h = bh & (HH - 1), t = threadIdx.x;
  const float* zrow = zg + (size_t)bh * LL;
  int c0 = t >> 2, i0 = (t & 3) * 16;
  {
    const float4* zsrc = (const float4*)(zrow + c0 * 64 + i0);
    #pragma unroll
    for (int q = 0; q < 4; ++q) {
      float4 v = zsrc[q];
      float vals[4] = {v.x, v.y, v.z, v.w};
      ushort4 hv, lv;
      u16 hh0 = f2bf(vals[0]); hv.x = hh0; lv.x = f2bf(vals[0] - bf2f(hh0));
      u16 hh1 = f2bf(vals[1]); hv.y = hh1; lv.y = f2bf(vals[1] - bf2f(hh1));
      u16 hh2 = f2bf(vals[2]); hv.z = hh2; lv.z = f2bf(vals[2] - bf2f(hh2));
      u16 hh3 = f2bf(vals[3]); hv.w = hh3; lv.w = f2bf(vals[3] - bf2f(hh3));
      *(ushort4*)&zh[c0 * 68 + i0 + q * 4] = hv;
      *(ushort4*)&zl[c0 * 68 + i0 + q * 4] = lv;
    }
  }
  __syncthreads();
  int wv = t >> 6, lane = t & 63, row16 = lane & 15, kgrp = lane >> 4;
  // ---- Phase A: S_ends = M @ Z ----
  {
    const u16* MhR = Mh + ((size_t)h * 64 + wv * 16 + row16) * 64;
    const u16* MlR = Ml + ((size_t)h * 64 + wv * 16 + row16) * 64;
    #pragma unroll
    for (int ct = 0; ct < 4; ++ct) {
      f32x4 acc = (f32x4){0.f, 0.f, 0.f, 0.f};
      int cc = ct * 16 + row16;
      #pragma unroll
      for (int kh = 0; kh < 2; ++kh) {
        int kb = kh * 32 + kgrp * 4;
        short8 Ah = ld8(MhR + kb);
        short8 Al = ld8(MlR + kb);
        short8 Bh = ld8(&zh[cc * 68 + kb]);
        short8 Bl = ld8(&zl[cc * 68 + kb]);
        acc = __builtin_amdgcn_mfma_f32_16x16x32_bf16(Ah, Bh, acc, 0, 0, 0);
        acc = __builtin_amdgcn_mfma_f32_16x16x32_bf16(Ah, Bl, acc, 0, 0, 0);
        acc = __builtin_amdgcn_mfma_f32_16x16x32_bf16(Al, Bh, acc, 0, 0, 0);
      }
      #pragma unroll
      for (int r = 0; r < 4; ++r)
        st[cc * 68 + wv * 16 + kgrp * 4 + r] = acc[r];
    }
  }
  __syncthreads();
  // ---- scan over 64 chunks (KS), states [2n]=re [2n+1]=im, multiplier w^64 ----
  {
    int sc = t >> 2, sub = t & 3;
    float xr[8], xi[8], pr[8], pi[8];
    #pragma unroll
    for (int k = 0; k < 8; ++k) {
      int n = sub * 8 + k;
      xr[k] = st[sc * 68 + 2 * n];
      xi[k] = st[sc * 68 + 2 * n + 1];
      pr[k] = coef[4 * HN + h * 32 + n];
      pi[k] = coef[5 * HN + h * 32 + n];
    }
    for (int d = 1; d < 64; d <<= 1) {
      float qr[8], qi[8];
      if (sc >= d) {
        #pragma unroll
        for (int k = 0; k < 8; ++k) {
          int n = sub * 8 + k;
          qr[k] = st[(sc - d) * 68 + 2 * n];
          qi[k] = st[(sc - d) * 68 + 2 * n + 1];
        }
      }
      __syncthreads();
      if (sc >= d) {
        #pragma unroll
        for (int k = 0; k < 8; ++k) {
          xr[k] = fmaf(pr[k], qr[k], fmaf(-pi[k], qi[k], xr[k]));
          xi[k] = fmaf(pr[k], qi[k], fmaf(pi[k], qr[k], xi[k]));
        }
      }
      #pragma unroll
      for (int k = 0; k < 8; ++k) {
        float t0 = pr[k] * pr[k] - pi[k] * pi[k];
        pi[k] = 2.f * pr[k] * pi[k];
        pr[k] = t0;
      }
      #pragma unroll
      for (int k = 0; k < 8; ++k) {
        int n = sub * 8 + k;
        st[sc * 68 + 2 * n] = xr[k];
        st[sc * 68 + 2 * n + 1] = xi[k];
      }
      __syncthreads();
    }
    // S_init[c] = inclusive prefix of c-1 -> hi/lo planes
    #pragma unroll
    for (int q = 0; q < 16; ++q) {
      int dim = sub * 16 + q;
      float v = (sc == 0) ? 0.f : st[(sc - 1) * 68 + dim];
      u16 hi = f2bf(v);
      sh[sc * 68 + dim] = hi;
      sl[sc * 68 + dim] = f2bf(v - bf2f(hi));
    }
  }
  __syncthreads();
  // ---- Phase B: Y = T @ Z + E @ S_init ----
  f32x4 y[4];
  {
    const u16* ThR = Th + ((size_t)h * 64 + wv * 16 + row16) * 64;
    const u16* TlR = Tl + ((size_t)h * 64 + wv * 16 + row16) * 64;
    const u16* EhR = Eh + ((size_t)h * 64 + wv * 16 + row16) * 64;
    const u16* ElR = El + ((size_t)h * 64 + wv * 16 + row16) * 64;
    #pragma unroll
    for (int ct = 0; ct < 4; ++ct) {
      f32x4 acc = (f32x4){0.f, 0.f, 0.f, 0.f};
      int cc = ct * 16 + row16;
      #pragma unroll
      for (int kh = 0; kh < 2; ++kh) {
        int kb = kh * 32 + kgrp * 4;
        short8 Ah = ld8(ThR + kb);
        short8 Al = ld8(TlR + kb);
        short8 Bh = ld8(&zh[cc * 68 + kb]);
        short8 Bl = ld8(&zl[cc * 68 + kb]);
        acc = __builtin_amdgcn_mfma_f32_16x16x32_bf16(Ah, Bh, acc, 0, 0, 0);
        acc = __builtin_amdgcn_mfma_f32_16x16x32_bf16(Ah, Bl, acc, 0, 0, 0);
        acc = __builtin_amdgcn_mfma_f32_16x16x32_bf16(Al, Bh, acc, 0, 0, 0);
        short8 Ch = ld8(EhR + kb);
        short8 Cl = ld8(ElR + kb);
        short8 Sh8 = ld8(&sh[cc * 68 + kb]);
        short8 Sl8 = ld8(&sl[cc * 68 + kb]);
        acc = __builtin_amdgcn_mfma_f32_16x16x32_bf16(Ch, Sh8, acc, 0, 0, 0);
        acc = __builtin_amdgcn_mfma_f32_16x16x32_bf16(Ch, Sl8, acc, 0, 0, 0);
        acc = __builtin_amdgcn_mfma_f32_16x16x32_bf16(Cl, Sh8, acc, 0, 0, 0);
      }
      y[ct] = acc;
    }
  }
  // ---- epilogue: v = z*D + y, gelu, pack; transpose via st for coalesced store ----
  {
    float Dh = Dvec[h];
    unsigned int* stu = (unsigned int*)st;
    #pragma unroll
    for (int ct = 0; ct < 4; ++ct) {
      int cc = ct * 16 + row16;
      #pragma unroll
      for (int r = 0; r < 4; ++r) {
        int j = wv * 16 + kgrp * 4 + r;
        float zf = bf2f(zh[cc * 68 + j]) + bf2f(zl[cc * 68 + j]);
        float v = fmaf(zf, Dh, y[ct][r]);
        float u = 1.5957691216057308f * fmaf(0.044715f * v, v * v, v);
        v = v / (1.f + __expf(-u));
        stu[cc * 68 + j] = packsplit(v);
      }
    }
  }
  __syncthreads();
  {
    unsigned int* grow = gout + (size_t)bh * LL;
    const unsigned int* stu = (const unsigned int*)st;
    #pragma unroll
    for (int q = 0; q < 4; ++q) {
      uint4 v = *(const uint4*)&stu[c0 * 68 + i0 + q * 4];
      *(uint4*)&grow[c0 * 64 + i0 + q * 4] = v;
    }
  }
}

// ---------------- MFMA matmul + bias + residual + LayerNorm (round-3 proven) ----------------
__global__ __launch_bounds__(256, 4) void mm_mfma_ln_kernel(
    const unsigned int* __restrict__ gp, float* __restrict__ h_buf,
    const unsigned int* __restrict__ Wp, const float* __restrict__ bo,
    const float* __restrict__ lw, const float* __restrict__ lb) {
  __shared__ unsigned int gt[BN * HH];
  __shared__ float red_s[4][BN];
  __shared__ float red_q[4][BN];
  int blk = blockIdx.x;
  int b = blk >> 7;
  int l0 = (blk & 127) * BN;
  int t = threadIdx.x;
  const unsigned int* gbase = gp + (size_t)b * HH * LL + l0;
  #pragma unroll
  for (int p = 0; p < 4; ++p) {
    int hh = p * 64 + (t >> 2);
    int lq = (t & 3) * 8;
    const uint4* src = (const uint4*)(gbase + (size_t)hh * LL + lq);
    uint4 v0 = src[0];
    uint4 v1 = src[1];
    unsigned int vals[8] = {v0.x, v0.y, v0.z, v0.w, v1.x, v1.y, v1.z, v1.w};
    #pragma unroll
    for (int j = 0; j < 8; ++j) {
      int l = lq + j;
      int xm = (l & 7) ^ ((l >> 3) & 3);
      int g4 = (hh >> 2) ^ xm;
      gt[l * HH + g4 * 4 + (hh & 3)] = vals[j];
    }
  }
  __syncthreads();
  int wv = t >> 6, lane = t & 63;
  int row16 = lane & 15, kgrp = lane >> 4;
  f32x4 acc[4][2];
  #pragma unroll
  for (int di = 0; di < 4; ++di)
    #pragma unroll
    for (int li = 0; li < 2; ++li)
      acc[di][li] = (f32x4){0.f, 0.f, 0.f, 0.f};
  const unsigned int* wbase = Wp + (size_t)(wv * 64) * HH;
  #pragma unroll 2
  for (int ks = 0; ks < 8; ++ks) {
    int h0 = ks * 32;
    short8 Bhi[2], Blo[2];
    #pragma unroll
    for (int li = 0; li < 2; ++li) {
      int l = li * 16 + row16;
      int xm = (l & 7) ^ ((l >> 3) & 3);
      int g4a = ((h0 >> 2) + kgrp) ^ xm;
      int g4b = ((h0 >> 2) + kgrp + 4) ^ xm;
      uint4 pa = *(const uint4*)&gt[l * HH + g4a * 4];
      uint4 pb = *(const uint4*)&gt[l * HH + g4b * 4];
      union { int i[4]; short8 s; } uh, ul;
      uh.i[0] = (int)((pa.x >> 16) | (pa.y & 0xFFFF0000u));
      uh.i[1] = (int)((pa.z >> 16) | (pa.w & 0xFFFF0000u));
      uh.i[2] = (int)((pb.x >> 16) | (pb.y & 0xFFFF0000u));
      uh.i[3] = (int)((pb.z >> 16) | (pb.w & 0xFFFF0000u));
      ul.i[0] = (int)((pa.x & 0xFFFFu) | (pa.y << 16));
      ul.i[1] = (int)((pa.z & 0xFFFFu) | (pa.w << 16));
      ul.i[2] = (int)((pb.x & 0xFFFFu) | (pb.y << 16));
      ul.i[3] = (int)((pb.z & 0xFFFFu) | (pb.w << 16));
      Bhi[li] = uh.s; Blo[li] = ul.s;
    }
    #pragma unroll
    for (int di = 0; di < 4; ++di) {
      int d = di * 16 + row16;
      const unsigned int* wr = wbase + (size_t)d * HH + h0 + kgrp * 4;
      uint4 pa = *(const uint4*)wr;
      uint4 pb = *(const uint4*)(wr + 16);
      union { int i[4]; short8 s; } uh, ul;
      uh.i[0] = (int)((pa.x >> 16) | (pa.y & 0xFFFF0000u));
      uh.i[1] = (int)((pa.z >> 16) | (pa.w & 0xFFFF0000u));
      uh.i[2] = (int)((pb.x >> 16) | (pb.y & 0xFFFF0000u));
      uh.i[3] = (int)((pb.z >> 16) | (pb.w & 0xFFFF0000u));
      ul.i[0] = (int)((pa.x & 0xFFFFu) | (pa.y << 16));
      ul.i[1] = (int)((pa.z & 0xFFFFu) | (pa.w << 16));
      ul.i[2] = (int)((pb.x & 0xFFFFu) | (pb.y << 16));
      ul.i[3] = (int)((pb.z & 0xFFFFu) | (pb.w << 16));
      short8 Ahi = uh.s, Alo = ul.s;
      #pragma unroll
      for (int li = 0; li < 2; ++li) {
        acc[di][li] = __builtin_amdgcn_mfma_f32_16x16x32_bf16(Ahi, Bhi[li], acc[di][li], 0, 0, 0);
        acc[di][li] = __builtin_amdgcn_mfma_f32_16x16x32_bf16(Ahi, Blo[li], acc[di][li], 0, 0, 0);
        acc[di][li] = __builtin_amdgcn_mfma_f32_16x16x32_bf16(Alo, Bhi[li], acc[di][li], 0, 0, 0);
      }
    }
  }
  const float* hb = h_buf + (size_t)b * HH * LL + l0;
  #pragma unroll
  for (int di = 0; di < 4; ++di) {
    #pragma unroll
    for (int r = 0; r < 4; ++r) {
      int d = wv * 64 + di * 16 + kgrp * 4 + r;
      float bov = bo[d];
      #pragma unroll
      for (int li = 0; li < 2; ++li) {
        int l = li * 16 + row16;
        acc[di][li][r] += bov + hb[(size_t)d * LL + l];
      }
    }
  }
  #pragma unroll
  for (int li = 0; li < 2; ++li) {
    float s = 0.f, q = 0.f;
    #pragma unroll
    for (int di = 0; di < 4; ++di)
      #pragma unroll
      for (int r = 0; r < 4; ++r) {
        float v = acc[di][li][r];
        s += v;
        q = fmaf(v, v, q);
      }
    s += __shfl_xor(s, 16); s += __shfl_xor(s, 32);
    q += __shfl_xor(q, 16); q += __shfl_xor(q, 32);
    if (lane < 16) {
      red_s[wv][li * 16 + lane] = s;
      red_q[wv][li * 16 + lane] = q;
    }
  }
  __syncthreads();
  float mu[2], rstd[2];
  #pragma unroll
  for (int li = 0; li < 2; ++li) {
    int cl = li * 16 + row16;
    float s = red_s[0][cl] + red_s[1][cl] + red_s[2][cl] + red_s[3][cl];
    float q = red_q[0][cl] + red_q[1][cl] + red_q[2][cl] + red_q[3][cl];
    float m = s * (1.f / 256.f);
    float var = q * (1.f / 256.f) - m * m;
    mu[li] = m;
    rstd[li] = rsqrtf(var + 1e-5f);
  }
  float* hw = h_buf + (size_t)b * HH * LL + l0;
  #pragma unroll
  for (int di = 0; di < 4; ++di) {
    #pragma unroll
    for (int r = 0; r < 4; ++r) {
      int d = wv * 64 + di * 16 + kgrp * 4 + r;
      float lwv = lw[d], lbv = lb[d];
      #pragma unroll
      for (int li = 0; li < 2; ++li) {
        int l = li * 16 + row16;
        hw[(size_t)d * LL + l] = (acc[di][li][r] - mu[li]) * rstd[li] * lwv + lbv;
      }
    }
  }
}

// ---------------- decoder ----------------
__global__ __launch_bounds__(256) void dec_kernel(
    const float* __restrict__ hbuf, const float* __restrict__ dw,
    const float* __restrict__ db, float* __restrict__ outp) {
  __shared__ float dwl[HH * DIN];
  int blk = blockIdx.x;
  int b = blk >> 4;
  int l0 = (blk & 15) * 256;
  int t = threadIdx.x;
  #pragma unroll
  for (int p = 0; p < 16; ++p) dwl[p * 256 + t] = dw[p * 256 + t];
  __syncthreads();
  float acc[DIN];
  #pragma unroll
  for (int d = 0; d < DIN; ++d) acc[d] = db[d];
  const float* hb = hbuf + (size_t)b * HH * LL + l0;
  for (int hh = 0; hh < HH; ++hh) {
    float v = hb[(size_t)hh * LL + t];
    #pragma unroll
    for (int d = 0; d < DIN; ++d)
      acc[d] = fmaf(v, dwl[hh * DIN + d], acc[d]);
  }
  float* ob = outp + (size_t)b * DIN * LL + l0;
  #pragma unroll
  for (int d = 0; d < DIN; ++d) ob[(size_t)d * LL + t] = acc[d];
}

extern "C" void kernel_launch(void* const* d_in, const int* in_sizes, int n_in,
                              void* d_out, int out_size, void* d_ws, size_t ws_size,
                              hipStream_t stream) {
  const float* x      = (const float*)d_in[0];
  const float* enc_w  = (const float*)d_in[1];
  const float* enc_b  = (const float*)d_in[2];
  const float* log_dt = (const float*)d_in[3];
  const float* A_re   = (const float*)d_in[4];
  const float* A_im   = (const float*)d_in[5];
  const float* C_re   = (const float*)d_in[6];
  const float* C_im   = (const float*)d_in[7];
  const float* Dv     = (const float*)d_in[8];
  const float* W_out  = (const float*)d_in[9];
  const float* b_out  = (const float*)d_in[10];
  const float* ln_w   = (const float*)d_in[11];
  const float* ln_b   = (const float*)d_in[12];
  const float* dec_w  = (const float*)d_in[13];
  const float* dec_b  = (const float*)d_in[14];
  float* out = (float*)d_out;

  float* h_buf = (float*)d_ws;
  unsigned int* g_pack = (unsigned int*)(h_buf + (size_t)Bb * HH * LL);
  float* coef = (float*)(g_pack + (size_t)Bb * HH * LL);
  unsigned int* Wp = (unsigned int*)(coef + 6 * HN);
  u16* Tp = (u16*)(Wp + HH * HH);
  const size_t PLANE = (size_t)HH * 64 * 64;
  u16* Th = Tp;
  u16* Tl = Tp + PLANE;
  u16* Mh = Tp + 2 * PLANE;
  u16* Ml = Tp + 3 * PLANE;
  u16* Eh = Tp + 4 * PLANE;
  u16* El = Tp + 5 * PLANE;

  enc_kernel<<<Bb * HH * (LL / 256), 256, 0, stream>>>(x, enc_w, enc_b, h_buf);
  for (int i = 0; i < NLAY; ++i) {
    coef_kernel<<<HN / 256, 256, 0, stream>>>(log_dt + i * HH, A_re + i * HN,
                                              A_im + i * HN, C_re + i * HN,
                                              C_im + i * HN, coef);
    basis_kernel<<<HH, 256, 0, stream>>>(coef, Th, Tl, Mh, Ml, Eh, El);
    wpack_kernel<<<HH * HH / 256, 256, 0, stream>>>(W_out + (size_t)i * HH * HH, Wp);
    s4_mfma_kernel<<<Bb * HH, 256, 0, stream>>>(h_buf, coef, Dv + i * HH,
                                                Th, Tl, Mh, Ml, Eh, El, g_pack);
    mm_mfma_ln_kernel<<<Bb * (LL / BN), 256, 0, stream>>>(
        g_pack, h_buf, Wp, b_out + i * HH, ln_w + i * HH, ln_b + i * HH);
  }
  dec_kernel<<<Bb * (LL / 256), 256, 0, stream>>>(h_buf, dec_w, dec_b, out);
}